// Round 1
// baseline (264.337 us; speedup 1.0000x reference)
//
#include <hip/hip_runtime.h>
#include <cmath>

namespace {
constexpr int NB   = 256;  // batch N
constexpr int CI   = 64;   // in channels
constexpr int CO   = 64;   // out channels
constexpr int TT_  = 64;   // time steps
constexpr int V    = 25;   // vertices
constexpr int REL  = 8;    // rel channels
constexpr int CC   = 16;   // c-chunk per k2 block
constexpr int TTIL = 16;   // t-tile in k2
}

// K1: per-n, compute x1[r][u], x2[r][v] (each REL*V) into ws.
// ws layout: ws[n*2*REL*V + 0..199] = x1, [+200..399] = x2
__global__ __launch_bounds__(1024) void k1_x12(
    const float* __restrict__ x,
    const float* __restrict__ w1, const float* __restrict__ b1,
    const float* __restrict__ w2, const float* __restrict__ b2,
    float* __restrict__ ws) {
  const int n = blockIdx.x;
  const int tid = threadIdx.x;
  __shared__ float xsum[CI][V];   // 6.4 KB

  for (int idx = tid; idx < CI * V; idx += 1024) (&xsum[0][0])[idx] = 0.f;
  __syncthreads();

  // coalesced float4 streaming of x[n] (CI*TT_*V = 102400 floats), LDS atomic reduce over t
  const float4* xb = reinterpret_cast<const float4*>(x + (size_t)n * (CI * TT_ * V));
  const int nvec = CI * TT_ * V / 4;  // 25600
  for (int r4 = tid; r4 < nvec; r4 += 1024) {
    float4 val = xb[r4];
    int e   = r4 * 4;
    int i   = e / (TT_ * V);
    int rem = e % (TT_ * V);      // rem..rem+3 stay within channel i (1600 % 4 == 0)
    atomicAdd(&xsum[i][rem % V],       val.x);
    atomicAdd(&xsum[i][(rem + 1) % V], val.y);
    atomicAdd(&xsum[i][(rem + 2) % V], val.z);
    atomicAdd(&xsum[i][(rem + 3) % V], val.w);
  }
  __syncthreads();

  // x1[r][v] = (sum_i w1[r,i]*xsum[i][v])/T + b1[r]; same for x2
  float* wsn = ws + (size_t)n * (2 * REL * V);
  for (int idx = tid; idx < REL * V; idx += 1024) {
    int r = idx / V, v = idx % V;
    float a1 = 0.f, a2 = 0.f;
    #pragma unroll
    for (int i = 0; i < CI; ++i) {
      float xs = xsum[i][v];
      a1 = fmaf(w1[r * CI + i], xs, a1);
      a2 = fmaf(w2[r * CI + i], xs, a2);
    }
    wsn[idx]           = a1 * (1.f / TT_) + b1[r];
    wsn[REL * V + idx] = a2 * (1.f / TT_) + b2[r];
  }
}

// K2: per (n, c-chunk of CC): build Afull chunk in LDS, then t-tiled
// inputs-compute + graph-conv.
__global__ __launch_bounds__(512) void k2_out(
    const float* __restrict__ x, const float* __restrict__ A,
    const float* __restrict__ w3, const float* __restrict__ b3,
    const float* __restrict__ wr, const float* __restrict__ br,
    const float* __restrict__ ws, float* __restrict__ out) {
  const int cb  = blockIdx.x;        // 0..CO/CC-1
  const int n   = blockIdx.y;        // 0..NB-1
  const int tid = threadIdx.x;       // 0..511
  const int c0  = cb * CC;

  __shared__ float Af[CC][V * V];        // 40000 B
  __shared__ float wrs[CI][CC];          // 4096 B (transposed wr chunk)
  __shared__ float inp[CC][TTIL][V];     // 25600 B (also reused as d-buffer)

  // stage wr chunk transposed: wrs[i][cc] = wr[c0+cc][i]
  for (int idx = tid; idx < CI * CC; idx += 512) {
    int i = idx / CC, cc = idx % CC;
    wrs[i][cc] = wr[(size_t)(c0 + cc) * CI + i];
  }

  // d[r][u][v] = tanh(x1[r][u] - x2[r][v]) into the inp region (5000 floats <= 6400)
  float* dbuf = &inp[0][0][0];
  const float* x1n = ws + (size_t)n * (2 * REL * V);
  const float* x2n = x1n + REL * V;
  for (int idx = tid; idx < REL * V * V; idx += 512) {
    int r = idx / (V * V);
    int rem = idx % (V * V);
    dbuf[idx] = tanhf(x1n[r * V + rem / V] - x2n[r * V + rem % V]);
  }
  __syncthreads();

  // Af[cc][u*V+v] = A[u][v] + b3[c] + sum_r w3[c][r]*d[r][u][v]
  for (int idx = tid; idx < CC * V * V; idx += 512) {
    int cc = idx / (V * V);
    int rem = idx % (V * V);
    float acc = A[rem] + b3[c0 + cc];
    #pragma unroll
    for (int r = 0; r < REL; ++r)
      acc = fmaf(w3[(c0 + cc) * REL + r], dbuf[r * V * V + rem], acc);
    Af[cc][rem] = acc;
  }
  __syncthreads();

  // pass-B ownership: thread = (cc_b, u), keep Afull row in 25 regs
  const int cc_b = tid >> 5;      // 0..15
  const int u    = tid & 31;      // 0..31, active if < 25
  float af[V];
  if (u < V) {
    #pragma unroll
    for (int v = 0; v < V; ++v) af[v] = Af[cc_b][u * V + v];
  }

  const float* xn = x + (size_t)n * (CI * TT_ * V);

  for (int t0 = 0; t0 < TT_; t0 += TTIL) {
    // ---- pass A: inputs tile: inp[cc][t][v] = sum_i wr[c,i]*x[n,i,t0+t,v] + br[c]
    if (tid < TTIL * V) {                     // 400 tasks
      float acc[CC];
      #pragma unroll
      for (int cc = 0; cc < CC; ++cc) acc[cc] = 0.f;
      const float* xp = xn + t0 * V + tid;    // coalesced: 400 consecutive floats per i
      #pragma unroll 4
      for (int i = 0; i < CI; ++i) {
        float xv = xp[(size_t)i * (TT_ * V)];
        #pragma unroll
        for (int cc = 0; cc < CC; ++cc)
          acc[cc] = fmaf(wrs[i][cc], xv, acc[cc]);
      }
      int tt = tid / V, v = tid % V;
      #pragma unroll
      for (int cc = 0; cc < CC; ++cc)
        inp[cc][tt][v] = acc[cc] + br[c0 + cc];
    }
    __syncthreads();

    // ---- pass B: out[n,c,t0+t,u] = sum_v af[v]*inp[cc][t][v]
    if (u < V) {
      #pragma unroll
      for (int t = 0; t < TTIL; ++t) {
        float acc = 0.f;
        #pragma unroll
        for (int v = 0; v < V; ++v)
          acc = fmaf(af[v], inp[cc_b][t][v], acc);
        out[(((size_t)n * CO + (c0 + cc_b)) * TT_ + (t0 + t)) * V + u] = acc;
      }
    }
    __syncthreads();
  }
}

extern "C" void kernel_launch(void* const* d_in, const int* in_sizes, int n_in,
                              void* d_out, int out_size, void* d_ws, size_t ws_size,
                              hipStream_t stream) {
  (void)in_sizes; (void)n_in; (void)out_size; (void)ws_size;
  const float* x  = (const float*)d_in[0];
  const float* A  = (const float*)d_in[1];
  const float* w1 = (const float*)d_in[2];
  const float* b1 = (const float*)d_in[3];
  const float* w2 = (const float*)d_in[4];
  const float* b2 = (const float*)d_in[5];
  const float* w3 = (const float*)d_in[6];
  const float* b3 = (const float*)d_in[7];
  const float* wr = (const float*)d_in[8];
  const float* br = (const float*)d_in[9];
  float* out = (float*)d_out;
  float* ws  = (float*)d_ws;

  hipLaunchKernelGGL(k1_x12, dim3(NB), dim3(1024), 0, stream,
                     x, w1, b1, w2, b2, ws);
  hipLaunchKernelGGL(k2_out, dim3(CO / CC, NB), dim3(512), 0, stream,
                     x, A, w3, b3, wr, br, ws, out);
}

// Round 2
// 190.142 us; speedup vs baseline: 1.3902x; 1.3902x over previous
//
#include <hip/hip_runtime.h>
#include <cmath>

namespace {
constexpr int NB   = 256;  // batch N
constexpr int CI   = 64;   // in channels
constexpr int CO   = 64;   // out channels
constexpr int TT   = 64;   // time steps
constexpr int V    = 25;   // vertices
constexpr int VP   = 28;   // padded V (16B-aligned rows for float4 LDS reads)
constexpr int REL  = 8;    // rel channels
constexpr int CC   = 16;   // c-chunk per k2 block
constexpr int TTIL = 16;   // t-tile in k2
}

// ---------------------------------------------------------------------------
// K1: per-n, compute x1[r][u], x2[r][v] (each REL*V) into ws. No atomics:
// stage 8 channels into LDS (coalesced float4), column-reduce over t.
// ws layout: ws[n*2*REL*V + 0..199] = x1, [+200..399] = x2
// ---------------------------------------------------------------------------
__global__ __launch_bounds__(1024) void k1_x12(
    const float* __restrict__ x,
    const float* __restrict__ w1, const float* __restrict__ b1,
    const float* __restrict__ w2, const float* __restrict__ b2,
    float* __restrict__ ws) {
  const int n = blockIdx.x;
  const int tid = threadIdx.x;
  __shared__ __align__(16) float xs[8][TT * V];   // 51.2 KB staging
  __shared__ float xsum[CI][V];                   // 6.4 KB
  __shared__ float w12[2][REL][CI];               // 4 KB

  // stage w1/w2
  for (int idx = tid; idx < 2 * REL * CI; idx += 1024) {
    int half = idx / (REL * CI), rem = idx % (REL * CI);
    w12[half][rem / CI][rem % CI] = half ? w2[rem] : w1[rem];
  }

  const float4* xb = reinterpret_cast<const float4*>(x + (size_t)n * (CI * TT * V));
  float4* xsv = reinterpret_cast<float4*>(&xs[0][0]);
  constexpr int V4G = 8 * TT * V / 4;  // 3200 float4 per group

  for (int g = 0; g < 8; ++g) {
    __syncthreads();  // previous group's readers done before overwrite
    for (int idx = tid; idx < V4G; idx += 1024)
      xsv[idx] = xb[g * V4G + idx];
    __syncthreads();
    if (tid < 8 * V) {                 // 200 reducers: (ch, v)
      int ch = tid / V, v = tid % V;
      float acc = 0.f;
      #pragma unroll
      for (int t = 0; t < TT; ++t) acc += xs[ch][t * V + v];
      xsum[g * 8 + ch][v] = acc;
    }
  }
  __syncthreads();

  // x1[r][v] = (sum_i w1[r,i]*xsum[i][v])/T + b1[r]; same for x2
  if (tid < 2 * REL * V) {
    int half = tid / (REL * V), rem = tid % (REL * V);
    int r = rem / V, v = rem % V;
    float a = 0.f;
    #pragma unroll
    for (int i = 0; i < CI; ++i) a = fmaf(w12[half][r][i], xsum[i][v], a);
    ws[(size_t)n * (2 * REL * V) + tid] = a * (1.f / TT) + (half ? b2[r] : b1[r]);
  }
}

// ---------------------------------------------------------------------------
// K2: per (n, 16-channel chunk): d -> af registers -> t-tiled inputs + graphconv
// LDS: buf (28.7 KB, shared by d[8][25][28] then inp[16][16][28]) + wrs (4.2 KB)
// ---------------------------------------------------------------------------
__global__ __launch_bounds__(512) void k2_out(
    const float* __restrict__ x, const float* __restrict__ A,
    const float* __restrict__ w3, const float* __restrict__ b3,
    const float* __restrict__ wr, const float* __restrict__ br,
    const float* __restrict__ ws, float* __restrict__ out) {
  const int cb  = blockIdx.x;        // 0..3
  const int n   = blockIdx.y;        // 0..255
  const int tid = threadIdx.x;       // 0..511
  const int c0  = cb * CC;

  __shared__ __align__(16) float buf[CC * TTIL * VP];  // 28672 B (>= 8*25*28 = 5600 fl)
  __shared__ __align__(16) float wrs[CI + 1][CC];      // 4160 B; row CI = br chunk

  // --- stage wr chunk transposed + br
  for (int idx = tid; idx < CI * CC; idx += 512) {
    int cc = idx & (CC - 1), i = idx >> 4;
    wrs[i][cc] = wr[(size_t)(c0 + cc) * CI + i];
  }
  if (tid < CC) wrs[CI][tid] = br[c0 + tid];

  // --- d[r][u][v] = tanh(x1[r][u] - x2[r][v]) into buf (padded rows of VP)
  const float* x1n = ws + (size_t)n * (2 * REL * V);
  const float* x2n = x1n + REL * V;
  for (int idx = tid; idx < REL * V * V; idx += 512) {
    int r = idx / (V * V);
    int rem = idx % (V * V);
    int uu = rem / V, vv = rem % V;
    buf[(r * V + uu) * VP + vv] = tanhf(x1n[r * V + uu] - x2n[r * V + vv]);
  }
  __syncthreads();

  // --- af[v] registers per (cc,u) thread: A + b3 + sum_r w3*d
  const int cc_b = tid >> 5;      // 0..15
  const int u    = tid & 31;      // active if < 25
  float af[V];
  if (u < V) {
    float w3r[REL];
    #pragma unroll
    for (int r = 0; r < REL; ++r) w3r[r] = w3[(size_t)(c0 + cc_b) * REL + r];
    const float bias = b3[c0 + cc_b];
    #pragma unroll
    for (int v = 0; v < V; ++v) af[v] = A[u * V + v] + bias;
    #pragma unroll
    for (int r = 0; r < REL; ++r) {
      const float* drow = buf + (r * V + u) * VP;
      #pragma unroll
      for (int v = 0; v < V; ++v) af[v] = fmaf(w3r[r], drow[v], af[v]);
    }
  }
  __syncthreads();   // done reading buf-as-d; safe to overwrite as inp

  const float* xn = x + (size_t)n * (CI * TT * V);
  const float4* wv = reinterpret_cast<const float4*>(&wrs[0][0]);  // [i][cc4]

  for (int t0 = 0; t0 < TT; t0 += TTIL) {
    // ---- pass A: inp[cc][tt][v] = sum_i wr[c,i]*x[n,i,t0+tt,v] + br[c]
    if (tid < TTIL * V) {                     // 400 tasks, (tt,v) = tid
      const int tt = tid / V, v = tid % V;
      float acc[CC];
      #pragma unroll
      for (int cc = 0; cc < CC; ++cc) acc[cc] = 0.f;
      const float* xp = xn + t0 * V + tid;    // wave-consecutive: fully coalesced
      #pragma unroll 4
      for (int i = 0; i < CI; ++i) {
        float xv = xp[(size_t)i * (TT * V)];
        float4 wa = wv[i * 4 + 0];
        float4 wb = wv[i * 4 + 1];
        float4 wc = wv[i * 4 + 2];
        float4 wd = wv[i * 4 + 3];
        acc[0]  = fmaf(wa.x, xv, acc[0]);  acc[1]  = fmaf(wa.y, xv, acc[1]);
        acc[2]  = fmaf(wa.z, xv, acc[2]);  acc[3]  = fmaf(wa.w, xv, acc[3]);
        acc[4]  = fmaf(wb.x, xv, acc[4]);  acc[5]  = fmaf(wb.y, xv, acc[5]);
        acc[6]  = fmaf(wb.z, xv, acc[6]);  acc[7]  = fmaf(wb.w, xv, acc[7]);
        acc[8]  = fmaf(wc.x, xv, acc[8]);  acc[9]  = fmaf(wc.y, xv, acc[9]);
        acc[10] = fmaf(wc.z, xv, acc[10]); acc[11] = fmaf(wc.w, xv, acc[11]);
        acc[12] = fmaf(wd.x, xv, acc[12]); acc[13] = fmaf(wd.y, xv, acc[13]);
        acc[14] = fmaf(wd.z, xv, acc[14]); acc[15] = fmaf(wd.w, xv, acc[15]);
      }
      #pragma unroll
      for (int cc = 0; cc < CC; ++cc)
        buf[(cc * TTIL + tt) * VP + v] = acc[cc] + wrs[CI][cc];
    }
    __syncthreads();

    // ---- pass B: out[n,c,t0+t,u] = sum_v af[v]*inp[cc][t][v]
    if (u < V) {
      #pragma unroll
      for (int t = 0; t < TTIL; ++t) {
        const float4* ip = reinterpret_cast<const float4*>(buf + (cc_b * TTIL + t) * VP);
        float4 p0 = ip[0], p1 = ip[1], p2 = ip[2], p3 = ip[3];
        float4 p4 = ip[4], p5 = ip[5], p6 = ip[6];
        float s;
        s = af[0] * p0.x;
        s = fmaf(af[1],  p0.y, s); s = fmaf(af[2],  p0.z, s); s = fmaf(af[3],  p0.w, s);
        s = fmaf(af[4],  p1.x, s); s = fmaf(af[5],  p1.y, s); s = fmaf(af[6],  p1.z, s);
        s = fmaf(af[7],  p1.w, s); s = fmaf(af[8],  p2.x, s); s = fmaf(af[9],  p2.y, s);
        s = fmaf(af[10], p2.z, s); s = fmaf(af[11], p2.w, s); s = fmaf(af[12], p3.x, s);
        s = fmaf(af[13], p3.y, s); s = fmaf(af[14], p3.z, s); s = fmaf(af[15], p3.w, s);
        s = fmaf(af[16], p4.x, s); s = fmaf(af[17], p4.y, s); s = fmaf(af[18], p4.z, s);
        s = fmaf(af[19], p4.w, s); s = fmaf(af[20], p5.x, s); s = fmaf(af[21], p5.y, s);
        s = fmaf(af[22], p5.z, s); s = fmaf(af[23], p5.w, s); s = fmaf(af[24], p6.x, s);
        out[(((size_t)n * CO + (c0 + cc_b)) * TT + (t0 + t)) * V + u] = s;
      }
    }
    __syncthreads();
  }
}

extern "C" void kernel_launch(void* const* d_in, const int* in_sizes, int n_in,
                              void* d_out, int out_size, void* d_ws, size_t ws_size,
                              hipStream_t stream) {
  (void)in_sizes; (void)n_in; (void)out_size; (void)ws_size;
  const float* x  = (const float*)d_in[0];
  const float* A  = (const float*)d_in[1];
  const float* w1 = (const float*)d_in[2];
  const float* b1 = (const float*)d_in[3];
  const float* w2 = (const float*)d_in[4];
  const float* b2 = (const float*)d_in[5];
  const float* w3 = (const float*)d_in[6];
  const float* b3 = (const float*)d_in[7];
  const float* wr = (const float*)d_in[8];
  const float* br = (const float*)d_in[9];
  float* out = (float*)d_out;
  float* ws  = (float*)d_ws;

  hipLaunchKernelGGL(k1_x12, dim3(NB), dim3(1024), 0, stream,
                     x, w1, b1, w2, b2, ws);
  hipLaunchKernelGGL(k2_out, dim3(CO / CC, NB), dim3(512), 0, stream,
                     x, A, w3, b3, wr, br, ws, out);
}